// Round 2
// baseline (356.876 us; speedup 1.0000x reference)
//
#include <hip/hip_runtime.h>

typedef unsigned int u32;
typedef unsigned short u16;

#define NPTS 1048576

// workspace dword layout (bf16 tap-pair tables, built by ga_prep from fp32 inputs)
#define WS_LINE_DW   0        // 3 * 511 * 64 = 98112 dwords: [line][i0][f] -> (tap0, tap1) bf16 pair
#define WS_VOL_DW    98112    // 100 * 64 = 6400 dwords: [(z*5+y)*4+x0][f] -> (x0, x0+1) pair
#define WS_PLANE_DW  104512   // 3 * 400 * 32 = 38400 dwords: [plane][row][swizzled chunk][2f]
#define WS_TOTAL_DW  142912
#define WS_TOTAL_BYTES (WS_TOTAL_DW * 4)

typedef short bf16x8 __attribute__((ext_vector_type(8)));
typedef float f32x4 __attribute__((ext_vector_type(4)));

__device__ __forceinline__ float bflo(u32 d) { return __uint_as_float(d << 16); }
__device__ __forceinline__ float bfhi(u32 d) { return __uint_as_float(d & 0xffff0000u); }
__device__ __forceinline__ u32 bfrne(float f) {
    u32 u = __float_as_uint(f);
    return (u + 0x7fffu + ((u >> 16) & 1u)) >> 16;
}

union U4 { uint4 v; u32 s[4]; };

// ---------------------------------------------------------------------------
// Prep: build feature-minor (transposed), tap-pair-duplicated bf16 tables in
// d_ws from the fp32 inputs.
// ---------------------------------------------------------------------------
__global__ __launch_bounds__(256) void ga_prep(
    const float* __restrict__ lx, const float* __restrict__ ly, const float* __restrict__ lz,
    const float* __restrict__ pxy, const float* __restrict__ pyz, const float* __restrict__ pzx,
    const float* __restrict__ vol, u32* __restrict__ ws)
{
    const int stride = gridDim.x * blockDim.x;
    for (int t = blockIdx.x * blockDim.x + threadIdx.x; t < WS_TOTAL_DW; t += stride) {
        if (t < 98112) {
            const int l = t / 32704;
            const int r = t - l * 32704;
            const int i0 = r >> 6;          // 0..510
            const int f  = r & 63;
            const float* L = (l == 0) ? lx : (l == 1) ? ly : lz;
            const u32 lo = bfrne(L[f*512 + i0]);
            const u32 hi = bfrne(L[f*512 + i0 + 1]);
            ws[t] = lo | (hi << 16);
        } else if (t < 104512) {
            const int r = t - 98112;
            const int f = r & 63;
            const int q = r >> 6;           // (z*5+y)*4 + x0
            const int x0 = q & 3;
            const int zy = q >> 2;
            const u32 lo = bfrne(vol[f*125 + zy*5 + x0]);
            const u32 hi = bfrne(vol[f*125 + zy*5 + x0 + 1]);
            ws[t] = lo | (hi << 16);
        } else {
            const int r = t - 104512;
            const int pp = r / 12800;
            const int rr = r - pp * 12800;
            const int row = rr >> 5;        // 0..399 (= y*20+x)
            const int c = rr & 31;          // dword within row (f pair index)
            const int chunk = c >> 2;       // 16-B chunk (8 features)
            const int ci = c & 3;
            const int pos = ((chunk ^ (row & 7)) << 2) + ci;  // XOR swizzle vs bank conflicts
            const float* P = (pp == 0) ? pxy : (pp == 1) ? pyz : pzx;
            const int f = c * 2;
            const u32 lo = bfrne(P[f*400 + row]);
            const u32 hi = bfrne(P[(f+1)*400 + row]);
            ws[104512 + pp*12800 + (row << 5) + pos] = lo | (hi << 16);
        }
    }
}

// ---------------------------------------------------------------------------
// Main: lane = (point p = lane&15, feature group fg = lane>>4).
// Each lane owns f in {8fg..8fg+7} u {32+8fg..32+8fg+7}  == MFMA A-frag layout.
// Planes from LDS (153.6 KB, swizzled); lines+volume from L2/L1 (pair tables).
// ---------------------------------------------------------------------------
__global__ __launch_bounds__(768, 3) void ga_main(
    const float* __restrict__ coords,
    const float* __restrict__ w1,
    const float* __restrict__ b1,
    const float* __restrict__ w2,
    const float* __restrict__ b2,
    const u32* __restrict__ ws,
    float* __restrict__ out)
{
    __shared__ u32 sP[38400];   // 153,600 B: 3 planes, [row][swizzled chunk][2f]
    const int tid = threadIdx.x;
    {
        const uint4* src = (const uint4*)(ws + WS_PLANE_DW);
        uint4* dst = (uint4*)sP;
        #pragma unroll
        for (int i = 0; i < 13; ++i) {
            int idx = tid + i * 768;
            if (idx < 9600) dst[idx] = src[idx];
        }
    }
    __syncthreads();

    const int lane = tid & 63;
    const int wave = tid >> 6;       // 0..11
    const int p    = lane & 15;
    const int fg   = lane >> 4;      // 0..3
    const int wgbase = blockIdx.x << 12;   // 4096 points per workgroup

    // w1 B-fragments: wfrag[t][h] holds bf16(w1[16t + p][h*32 + fg*8 + j])
    bf16x8 wfrag[4][2];
    #pragma unroll
    for (int t = 0; t < 4; ++t) {
        #pragma unroll
        for (int h = 0; h < 2; ++h) {
            const float* src = w1 + ((16*t + p)*64 + h*32 + fg*8);
            float4 f0 = *(const float4*)(src);
            float4 f1 = *(const float4*)(src + 4);
            union { u32 u[4]; bf16x8 b; } u;
            u.u[0] = bfrne(f0.x) | (bfrne(f0.y) << 16);
            u.u[1] = bfrne(f0.z) | (bfrne(f0.w) << 16);
            u.u[2] = bfrne(f1.x) | (bfrne(f1.y) << 16);
            u.u[3] = bfrne(f1.z) | (bfrne(f1.w) << 16);
            wfrag[t][h] = u.b;
        }
    }
    float b1v[4], w2v[4];
    #pragma unroll
    for (int t = 0; t < 4; ++t) { b1v[t] = b1[16*t + p]; w2v[t] = w2[16*t + p]; }
    const float b2v = b2[0];

    const char* wsb = (const char*)ws;
    const char* spb = (const char*)sP;

    for (int g = wave; g < 256; g += 12) {
        const int pbase = wgbase + (g << 4);
        const int pt = pbase + p;
        const float cx = coords[3*pt + 0];
        const float cy = coords[3*pt + 1];
        const float cz = coords[3*pt + 2];

        int lidx[3], pidx[3], vidx[3];
        float lww[3], lwm[3], pww[3], pwm[3], vww[3], vwm[3];
        {
            const float uu[3] = { (cx+1.f)*0.5f, (cy+1.f)*0.5f, (cz+1.f)*0.5f };
            #pragma unroll
            for (int c = 0; c < 3; ++c) {
                float pos = fminf(fmaxf(uu[c]*511.f, 0.f), 511.f);
                float i0 = fminf(floorf(pos), 510.f);
                lidx[c] = (int)i0; lww[c] = pos - i0; lwm[c] = 1.f - lww[c];
                float pq = fminf(fmaxf(uu[c]*19.f, 0.f), 19.f);
                float pi0 = fminf(floorf(pq), 18.f);
                pidx[c] = (int)pi0; pww[c] = pq - pi0; pwm[c] = 1.f - pww[c];
                float vq = fminf(fmaxf(uu[c]*4.f, 0.f), 4.f);
                float vi0 = fminf(floorf(vq), 3.f);
                vidx[c] = (int)vi0; vww[c] = vq - vi0; vwm[c] = 1.f - vww[c];
            }
        }
        // line table byte addresses (chunk A; chunk B = +128 B immediate)
        int laddr[3];
        #pragma unroll
        for (int c = 0; c < 3; ++c)
            laddr[c] = (c*32704 + lidx[c]*64 + fg*8) * 4;
        // plane corner weights + swizzled LDS row addresses
        // plane0=xy(gx=x,gy=y)  plane1=yz(gx=y,gy=z)  plane2=zx(gx=z,gy=x)
        float wq[3][4];
        int paddr[3][4];
        #pragma unroll
        for (int pp = 0; pp < 3; ++pp) {
            const int a = (pp==0)?0:(pp==1)?1:2;    // gx axis (col)
            const int b = (pp==0)?1:(pp==1)?2:0;    // gy axis (row)
            wq[pp][0] = pwm[b]*pwm[a]; wq[pp][1] = pwm[b]*pww[a];
            wq[pp][2] = pww[b]*pwm[a]; wq[pp][3] = pww[b]*pww[a];
            const int r00 = pidx[b]*20 + pidx[a];
            const int roff[4] = {0, 1, 20, 21};
            #pragma unroll
            for (int k = 0; k < 4; ++k) {
                const int r = r00 + roff[k];
                paddr[pp][k] = pp*51200 + r*128 + ((fg ^ (r & 7)) << 4);
            }
        }
        // volume weights + addresses (taps grouped as x-pairs, 4 (z,y) rows)
        float vwt0[4], vwt1[4];
        {
            const float zy[4] = { vwm[2]*vwm[1], vwm[2]*vww[1], vww[2]*vwm[1], vww[2]*vww[1] };
            #pragma unroll
            for (int t = 0; t < 4; ++t) { vwt0[t] = zy[t]*vwm[0]; vwt1[t] = zy[t]*vww[0]; }
        }
        const int q00 = (vidx[2]*5 + vidx[1])*4 + vidx[0];
        const int vaddr0 = (WS_VOL_DW + q00*64 + fg*8) * 4;

        u32 afrag[2][4];
        #pragma unroll
        for (int cc = 0; cc < 2; ++cc) {
            const int co = cc * 128;   // chunk B: +32 dwords in pair tables
            const int xo = cc * 64;    // chunk B in LDS: chunk idx ^4 -> byte ^64
            float fx[8], fy[8], fz[8], comb[8];
            // lines: one dword = (tap0, tap1) for one feature
            {
                U4 a0, a1, b0, b1_, c0, c1;
                a0.v = *(const uint4*)(wsb + laddr[0] + co);
                a1.v = *(const uint4*)(wsb + laddr[0] + co + 16);
                b0.v = *(const uint4*)(wsb + laddr[1] + co);
                b1_.v = *(const uint4*)(wsb + laddr[1] + co + 16);
                c0.v = *(const uint4*)(wsb + laddr[2] + co);
                c1.v = *(const uint4*)(wsb + laddr[2] + co + 16);
                #pragma unroll
                for (int j = 0; j < 8; ++j) {
                    const u32 dx = (j < 4) ? a0.s[j] : a1.s[j-4];
                    const u32 dy = (j < 4) ? b0.s[j] : b1_.s[j-4];
                    const u32 dz = (j < 4) ? c0.s[j] : c1.s[j-4];
                    fx[j] = fmaf(bfhi(dx), lww[0], bflo(dx) * lwm[0]);
                    fy[j] = fmaf(bfhi(dy), lww[1], bflo(dy) * lwm[1]);
                    fz[j] = fmaf(bfhi(dz), lww[2], bflo(dz) * lwm[2]);
                }
            }
            #pragma unroll
            for (int j = 0; j < 8; ++j) comb[j] = fx[j]*fy[j]*fz[j];
            // planes from LDS: one dword = 2 adjacent features at one tap
            #pragma unroll
            for (int pp = 0; pp < 3; ++pp) {
                U4 r0, r1, r2, r3;
                r0.v = *(const uint4*)(spb + (paddr[pp][0] ^ xo));
                r1.v = *(const uint4*)(spb + (paddr[pp][1] ^ xo));
                r2.v = *(const uint4*)(spb + (paddr[pp][2] ^ xo));
                r3.v = *(const uint4*)(spb + (paddr[pp][3] ^ xo));
                #pragma unroll
                for (int j = 0; j < 4; ++j) {
                    float ve = wq[pp][0] * bflo(r0.s[j]);
                    ve = fmaf(wq[pp][1], bflo(r1.s[j]), ve);
                    ve = fmaf(wq[pp][2], bflo(r2.s[j]), ve);
                    ve = fmaf(wq[pp][3], bflo(r3.s[j]), ve);
                    float vo = wq[pp][0] * bfhi(r0.s[j]);
                    vo = fmaf(wq[pp][1], bfhi(r1.s[j]), vo);
                    vo = fmaf(wq[pp][2], bfhi(r2.s[j]), vo);
                    vo = fmaf(wq[pp][3], bfhi(r3.s[j]), vo);
                    const float me = (pp==0) ? fz[2*j]   : (pp==1) ? fx[2*j]   : fy[2*j];
                    const float mo = (pp==0) ? fz[2*j+1] : (pp==1) ? fx[2*j+1] : fy[2*j+1];
                    comb[2*j]   = fmaf(ve, me, comb[2*j]);
                    comb[2*j+1] = fmaf(vo, mo, comb[2*j+1]);
                }
            }
            // volume: one dword = (x0, x0+1) pair for one feature
            #pragma unroll
            for (int t = 0; t < 4; ++t) {
                const int base = vaddr0 + (t >> 1)*5120 + (t & 1)*1024 + co;
                U4 a0, a1;
                a0.v = *(const uint4*)(wsb + base);
                a1.v = *(const uint4*)(wsb + base + 16);
                #pragma unroll
                for (int j = 0; j < 8; ++j) {
                    const u32 d = (j < 4) ? a0.s[j] : a1.s[j-4];
                    comb[j] = fmaf(bflo(d), vwt0[t], comb[j]);
                    comb[j] = fmaf(bfhi(d), vwt1[t], comb[j]);
                }
            }
            #pragma unroll
            for (int j = 0; j < 4; ++j)
                afrag[cc][j] = bfrne(comb[2*j]) | (bfrne(comb[2*j+1]) << 16);
        }
        // MLP layer 1: h[n,g] = sum_f comb[n,f] * w1[g,f]
        union { u32 u[4]; bf16x8 b; } A0, A1;
        #pragma unroll
        for (int j = 0; j < 4; ++j) { A0.u[j] = afrag[0][j]; A1.u[j] = afrag[1][j]; }
        f32x4 acc0 = {0.f,0.f,0.f,0.f};
        f32x4 acc1 = {0.f,0.f,0.f,0.f};
        f32x4 acc2 = {0.f,0.f,0.f,0.f};
        f32x4 acc3 = {0.f,0.f,0.f,0.f};
        acc0 = __builtin_amdgcn_mfma_f32_16x16x32_bf16(A0.b, wfrag[0][0], acc0, 0, 0, 0);
        acc0 = __builtin_amdgcn_mfma_f32_16x16x32_bf16(A1.b, wfrag[0][1], acc0, 0, 0, 0);
        acc1 = __builtin_amdgcn_mfma_f32_16x16x32_bf16(A0.b, wfrag[1][0], acc1, 0, 0, 0);
        acc1 = __builtin_amdgcn_mfma_f32_16x16x32_bf16(A1.b, wfrag[1][1], acc1, 0, 0, 0);
        acc2 = __builtin_amdgcn_mfma_f32_16x16x32_bf16(A0.b, wfrag[2][0], acc2, 0, 0, 0);
        acc2 = __builtin_amdgcn_mfma_f32_16x16x32_bf16(A1.b, wfrag[2][1], acc2, 0, 0, 0);
        acc3 = __builtin_amdgcn_mfma_f32_16x16x32_bf16(A0.b, wfrag[3][0], acc3, 0, 0, 0);
        acc3 = __builtin_amdgcn_mfma_f32_16x16x32_bf16(A1.b, wfrag[3][1], acc3, 0, 0, 0);
        // layer 2: relu + dot with w2, then reduce over the 16 C-layout columns
        float sr[4];
        #pragma unroll
        for (int r = 0; r < 4; ++r) {
            float s = fmaxf(acc0[r] + b1v[0], 0.f) * w2v[0];
            s = fmaf(fmaxf(acc1[r] + b1v[1], 0.f), w2v[1], s);
            s = fmaf(fmaxf(acc2[r] + b1v[2], 0.f), w2v[2], s);
            s = fmaf(fmaxf(acc3[r] + b1v[3], 0.f), w2v[3], s);
            sr[r] = s;
        }
        #pragma unroll
        for (int m = 1; m <= 8; m <<= 1) {
            #pragma unroll
            for (int r = 0; r < 4; ++r) sr[r] += __shfl_xor(sr[r], m, 64);
        }
        if (p == 0) {
            // this quad holds points pbase + fg*4 + {0,1,2,3}
            float4 o;
            o.x = sr[0] + b2v;
            o.y = sr[1] + b2v;
            o.z = sr[2] + b2v;
            o.w = sr[3] + b2v;
            *(float4*)(out + pbase + (fg << 2)) = o;
        }
    }
}

// ---------------------------------------------------------------------------
// Fallback (only if ws_size is too small): slow but correct, thread-per-point.
// ---------------------------------------------------------------------------
__global__ __launch_bounds__(256) void ga_naive(
    const float* __restrict__ coords,
    const float* __restrict__ lx, const float* __restrict__ ly, const float* __restrict__ lz,
    const float* __restrict__ pxy, const float* __restrict__ pyz, const float* __restrict__ pzx,
    const float* __restrict__ vol,
    const float* __restrict__ w1, const float* __restrict__ b1,
    const float* __restrict__ w2, const float* __restrict__ b2,
    float* __restrict__ out)
{
    const int n = blockIdx.x * blockDim.x + threadIdx.x;
    if (n >= NPTS) return;
    int lidx[3], pidx[3], vidx[3];
    float lww[3], lwm[3], pww[3], pwm[3], vww[3], vwm[3];
    for (int c = 0; c < 3; ++c) {
        const float cv = coords[3*n + c];
        const float u = (cv + 1.f)*0.5f;
        float pos = fminf(fmaxf(u*511.f, 0.f), 511.f);
        float i0 = fminf(floorf(pos), 510.f);
        lidx[c] = (int)i0; lww[c] = pos - i0; lwm[c] = 1.f - lww[c];
        float pq = fminf(fmaxf(u*19.f, 0.f), 19.f);
        float pi0 = fminf(floorf(pq), 18.f);
        pidx[c] = (int)pi0; pww[c] = pq - pi0; pwm[c] = 1.f - pww[c];
        float vq = fminf(fmaxf(u*4.f, 0.f), 4.f);
        float vi0 = fminf(floorf(vq), 3.f);
        vidx[c] = (int)vi0; vww[c] = vq - vi0; vwm[c] = 1.f - vww[c];
    }
    float comb[64];
    for (int f = 0; f < 64; ++f) {
        const float fxv = lwm[0]*lx[f*512+lidx[0]] + lww[0]*lx[f*512+lidx[0]+1];
        const float fyv = lwm[1]*ly[f*512+lidx[1]] + lww[1]*ly[f*512+lidx[1]+1];
        const float fzv = lwm[2]*lz[f*512+lidx[2]] + lww[2]*lz[f*512+lidx[2]+1];
        const int bxy = f*400 + pidx[1]*20 + pidx[0];
        const float pxyv = pwm[1]*pwm[0]*pxy[bxy]    + pwm[1]*pww[0]*pxy[bxy+1]
                         + pww[1]*pwm[0]*pxy[bxy+20] + pww[1]*pww[0]*pxy[bxy+21];
        const int byz = f*400 + pidx[2]*20 + pidx[1];
        const float pyzv = pwm[2]*pwm[1]*pyz[byz]    + pwm[2]*pww[1]*pyz[byz+1]
                         + pww[2]*pwm[1]*pyz[byz+20] + pww[2]*pww[1]*pyz[byz+21];
        const int bzx = f*400 + pidx[0]*20 + pidx[2];
        const float pzxv = pwm[0]*pwm[2]*pzx[bzx]    + pwm[0]*pww[2]*pzx[bzx+1]
                         + pww[0]*pwm[2]*pzx[bzx+20] + pww[0]*pww[2]*pzx[bzx+21];
        const int bv = f*125 + (vidx[2]*5 + vidx[1])*5 + vidx[0];
        float vv = 0.f;
        for (int dz = 0; dz < 2; ++dz)
            for (int dy = 0; dy < 2; ++dy)
                for (int dx = 0; dx < 2; ++dx) {
                    const float w = (dz ? vww[2] : vwm[2]) * (dy ? vww[1] : vwm[1]) * (dx ? vww[0] : vwm[0]);
                    vv += w * vol[bv + dz*25 + dy*5 + dx];
                }
        comb[f] = fxv*fyv*fzv + pxyv*fzv + pyzv*fxv + pzxv*fyv + vv;
    }
    float o = b2[0];
    for (int gg = 0; gg < 64; ++gg) {
        float h = b1[gg];
        for (int f = 0; f < 64; ++f) h = fmaf(comb[f], w1[gg*64 + f], h);
        o = fmaf(fmaxf(h, 0.f), w2[gg], o);
    }
    out[n] = o;
}

extern "C" void kernel_launch(void* const* d_in, const int* in_sizes, int n_in,
                              void* d_out, int out_size, void* d_ws, size_t ws_size,
                              hipStream_t stream)
{
    const float* coords = (const float*)d_in[0];
    const float* lx  = (const float*)d_in[1];
    const float* ly  = (const float*)d_in[2];
    const float* lz  = (const float*)d_in[3];
    const float* pxy = (const float*)d_in[4];
    const float* pyz = (const float*)d_in[5];
    const float* pzx = (const float*)d_in[6];
    const float* vol = (const float*)d_in[7];
    const float* w1  = (const float*)d_in[8];
    const float* b1  = (const float*)d_in[9];
    const float* w2  = (const float*)d_in[10];
    const float* b2  = (const float*)d_in[11];
    float* out = (float*)d_out;
    if (ws_size >= (size_t)WS_TOTAL_BYTES) {
        u32* ws = (u32*)d_ws;
        ga_prep<<<dim3(256), dim3(256), 0, stream>>>(lx, ly, lz, pxy, pyz, pzx, vol, ws);
        ga_main<<<dim3(256), dim3(768), 0, stream>>>(coords, w1, b1, w2, b2, ws, out);
    } else {
        ga_naive<<<dim3(4096), dim3(256), 0, stream>>>(coords, lx, ly, lz, pxy, pyz, pzx, vol,
                                                       w1, b1, w2, b2, out);
    }
}

// Round 3
// 307.044 us; speedup vs baseline: 1.1623x; 1.1623x over previous
//
#include <hip/hip_runtime.h>

typedef unsigned int u32;
typedef unsigned short u16;
typedef _Float16 half_t;
typedef half_t h2   __attribute__((ext_vector_type(2)));
typedef half_t f16x8 __attribute__((ext_vector_type(8)));
typedef float  f32x4 __attribute__((ext_vector_type(4)));

#define NPTS 1048576

// workspace dword layout (f16 feature-pair tables, built by ga_prep from fp32)
#define WS_LINE_DW   0        // 3*511*2*32 = 98112 dw: [line][i0][tap][fpair]
#define WS_VOL_DW    98112    // 125*32     =  4000 dw: [z*25+y*5+x][fpair]
#define WS_PLANE_DW  102112   // 3*400*32   = 38400 dw: [plane][row][swizzled chunk][fpair]
#define WS_TOTAL_DW  140512
#define WS_TOTAL_BYTES (WS_TOTAL_DW * 4)

__device__ __forceinline__ u32 pkh(float a, float b) {
    union { h2 h; u32 u; } r;
    r.h = (h2){(half_t)a, (half_t)b};
    return r.u;
}
__device__ __forceinline__ h2 bc(float w) {
    half_t h = (half_t)w;
    return (h2){h, h};
}

// ---------------------------------------------------------------------------
// Prep: fp32 inputs -> f16 feature-pair tables in d_ws.
// ---------------------------------------------------------------------------
__global__ __launch_bounds__(256) void ga_prep(
    const float* __restrict__ lx, const float* __restrict__ ly, const float* __restrict__ lz,
    const float* __restrict__ pxy, const float* __restrict__ pyz, const float* __restrict__ pzx,
    const float* __restrict__ vol, u32* __restrict__ ws)
{
    const int stride = gridDim.x * blockDim.x;
    for (int t = blockIdx.x * blockDim.x + threadIdx.x; t < WS_TOTAL_DW; t += stride) {
        if (t < WS_VOL_DW) {
            // lines: [l][i0][tap][fpair], dw = (f16(f=2fp), f16(f=2fp+1)) at tap
            const int l  = t / 32704;           // 511*64
            const int r  = t - l * 32704;
            const int i0 = r >> 6;              // 0..510
            const int w  = r & 63;
            const int tap = w >> 5;
            const int fp  = w & 31;
            const float* L = (l == 0) ? lx : (l == 1) ? ly : lz;
            ws[t] = pkh(L[(2*fp)*512 + i0 + tap], L[(2*fp+1)*512 + i0 + tap]);
        } else if (t < WS_PLANE_DW) {
            // volume: [vox][fpair]
            const int r = t - WS_VOL_DW;
            const int vox = r >> 5;
            const int fp  = r & 31;
            ws[t] = pkh(vol[(2*fp)*125 + vox], vol[(2*fp+1)*125 + vox]);
        } else {
            // planes: [pp][row][swizzled 16B-chunk][fpair-in-chunk]
            const int r  = t - WS_PLANE_DW;
            const int pp = r / 12800;
            const int rr = r - pp * 12800;
            const int row = rr >> 5;            // 0..399 (= y*20+x)
            const int c   = rr & 31;            // fpair index
            const int chunk = c >> 2;
            const int ci    = c & 3;
            const int pos = ((chunk ^ (row & 7)) << 2) + ci;  // XOR swizzle
            const float* P = (pp == 0) ? pxy : (pp == 1) ? pyz : pzx;
            const int f = c * 2;
            ws[WS_PLANE_DW + pp*12800 + (row << 5) + pos] =
                pkh(P[f*400 + row], P[(f+1)*400 + row]);
        }
    }
}

// ---------------------------------------------------------------------------
// Main: lane = (point p = lane&15, feature group fg = lane>>4).
// Packed-f16 feature math; comb lands directly as the f16 MFMA A-fragment.
// Planes from LDS (153.6 KB, swizzled); lines from L2; volume (16 KB) L1-hot.
// 1024-thread blocks -> 16 waves/CU (LDS caps us at 1 block/CU).
// ---------------------------------------------------------------------------
__global__ __launch_bounds__(1024, 4) void ga_main(
    const float* __restrict__ coords,
    const float* __restrict__ w1,
    const float* __restrict__ b1,
    const float* __restrict__ w2,
    const float* __restrict__ b2,
    const u32* __restrict__ ws,
    float* __restrict__ out)
{
    __shared__ u32 sP[38400];   // 153,600 B
    const int tid = threadIdx.x;
    {
        const uint4* src = (const uint4*)(ws + WS_PLANE_DW);
        uint4* dst = (uint4*)sP;
        #pragma unroll
        for (int i = 0; i < 10; ++i) {
            int idx = tid + i * 1024;
            if (idx < 9600) dst[idx] = src[idx];
        }
    }
    __syncthreads();

    const int lane = tid & 63;
    const int wave = tid >> 6;       // 0..15
    const int p    = lane & 15;
    const int fg   = lane >> 4;      // 0..3
    const int wgbase = blockIdx.x << 12;   // 4096 points per workgroup

    // w1 B-fragments (f16): wfrag[t][h][j] = f16(w1[16t + p][h*32 + fg*8 + j])
    f16x8 wfrag[4][2];
    #pragma unroll
    for (int t = 0; t < 4; ++t) {
        #pragma unroll
        for (int h = 0; h < 2; ++h) {
            const float* src = w1 + ((16*t + p)*64 + h*32 + fg*8);
            f16x8 w;
            #pragma unroll
            for (int e = 0; e < 8; ++e) w[e] = (half_t)src[e];
            wfrag[t][h] = w;
        }
    }
    float b1v[4], w2v[4];
    #pragma unroll
    for (int t = 0; t < 4; ++t) { b1v[t] = b1[16*t + p]; w2v[t] = w2[16*t + p]; }
    const float b2v = b2[0];

    const char* wsb = (const char*)ws;
    const char* spb = (const char*)sP;

    for (int g = wave; g < 256; g += 16) {
        const int pbase = wgbase + (g << 4);
        const int pt = pbase + p;
        const float cx = coords[3*pt + 0];
        const float cy = coords[3*pt + 1];
        const float cz = coords[3*pt + 2];

        int lidx[3], pidx[3], vidx[3];
        float lww[3], lwm[3], pww[3], pwm[3], vww[3], vwm[3];
        {
            const float uu[3] = { (cx+1.f)*0.5f, (cy+1.f)*0.5f, (cz+1.f)*0.5f };
            #pragma unroll
            for (int c = 0; c < 3; ++c) {
                float pos = fminf(fmaxf(uu[c]*511.f, 0.f), 511.f);
                float i0 = fminf(floorf(pos), 510.f);
                lidx[c] = (int)i0; lww[c] = pos - i0; lwm[c] = 1.f - lww[c];
                float pq = fminf(fmaxf(uu[c]*19.f, 0.f), 19.f);
                float pi0 = fminf(floorf(pq), 18.f);
                pidx[c] = (int)pi0; pww[c] = pq - pi0; pwm[c] = 1.f - pww[c];
                float vq = fminf(fmaxf(uu[c]*4.f, 0.f), 4.f);
                float vi0 = fminf(floorf(vq), 3.f);
                vidx[c] = (int)vi0; vww[c] = vq - vi0; vwm[c] = 1.f - vwm[c]*0.f - vww[c];
            }
        }
        // line byte bases: [c][i0] block = 256 B; tap1 at +128; cc chunk at +64
        int laddr[3];
        #pragma unroll
        for (int c = 0; c < 3; ++c)
            laddr[c] = (c*511 + lidx[c])*256 + fg*16;
        // plane corner weights + swizzled LDS base addresses
        // plane0=xy(gx=x,gy=y)  plane1=yz(gx=y,gy=z)  plane2=zx(gx=z,gy=x)
        float wqf[3][4];
        int paddr[3][4];
        #pragma unroll
        for (int pp = 0; pp < 3; ++pp) {
            const int a = (pp==0)?0:(pp==1)?1:2;    // gx axis (col)
            const int b = (pp==0)?1:(pp==1)?2:0;    // gy axis (row)
            wqf[pp][0] = pwm[b]*pwm[a]; wqf[pp][1] = pwm[b]*pww[a];
            wqf[pp][2] = pww[b]*pwm[a]; wqf[pp][3] = pww[b]*pww[a];
            const int r00 = pidx[b]*20 + pidx[a];
            const int roff[4] = {0, 1, 20, 21};
            #pragma unroll
            for (int k = 0; k < 4; ++k) {
                const int r = r00 + roff[k];
                paddr[pp][k] = pp*51200 + r*128 + ((fg ^ (r & 7)) << 4);
            }
        }
        // volume: 8 corner taps, base + immediate offsets {dz*3200 + dy*640 + dx*128}
        const int vox00 = (vidx[2]*5 + vidx[1])*5 + vidx[0];
        const int vbase = WS_VOL_DW*4 + vox00*128 + fg*16;
        float wvf[8];
        #pragma unroll
        for (int dz = 0; dz < 2; ++dz)
            #pragma unroll
            for (int dy = 0; dy < 2; ++dy)
                #pragma unroll
                for (int dx = 0; dx < 2; ++dx)
                    wvf[dz*4+dy*2+dx] = (dz?vww[2]:vwm[2])*(dy?vww[1]:vwm[1])*(dx?vww[0]:vwm[0]);

        // h2 weight broadcasts
        h2 wlm[3], wlw[3], wqb[3][4], wvb[8];
        #pragma unroll
        for (int c = 0; c < 3; ++c) { wlm[c] = bc(lwm[c]); wlw[c] = bc(lww[c]); }
        #pragma unroll
        for (int pp = 0; pp < 3; ++pp)
            #pragma unroll
            for (int k = 0; k < 4; ++k) wqb[pp][k] = bc(wqf[pp][k]);
        #pragma unroll
        for (int t = 0; t < 8; ++t) wvb[t] = bc(wvf[t]);

        union UH { uint4 v; h2 h[4]; };
        h2 comb[2][4];
        #pragma unroll
        for (int cc = 0; cc < 2; ++cc) {
            const int co = cc * 64;
            // lines
            UH X0, X1, Y0, Y1, Z0, Z1;
            X0.v = *(const uint4*)(wsb + laddr[0] + co);
            X1.v = *(const uint4*)(wsb + laddr[0] + co + 128);
            Y0.v = *(const uint4*)(wsb + laddr[1] + co);
            Y1.v = *(const uint4*)(wsb + laddr[1] + co + 128);
            Z0.v = *(const uint4*)(wsb + laddr[2] + co);
            Z1.v = *(const uint4*)(wsb + laddr[2] + co + 128);
            h2 fx[4], fy[4], fz[4];
            #pragma unroll
            for (int j = 0; j < 4; ++j) {
                fx[j] = X0.h[j]*wlm[0] + X1.h[j]*wlw[0];
                fy[j] = Y0.h[j]*wlm[1] + Y1.h[j]*wlw[1];
                fz[j] = Z0.h[j]*wlm[2] + Z1.h[j]*wlw[2];
            }
            #pragma unroll
            for (int j = 0; j < 4; ++j) comb[cc][j] = fx[j]*fy[j]*fz[j];
            // planes (LDS)
            #pragma unroll
            for (int pp = 0; pp < 3; ++pp) {
                UH r0, r1, r2, r3;
                r0.v = *(const uint4*)(spb + (paddr[pp][0] ^ co));
                r1.v = *(const uint4*)(spb + (paddr[pp][1] ^ co));
                r2.v = *(const uint4*)(spb + (paddr[pp][2] ^ co));
                r3.v = *(const uint4*)(spb + (paddr[pp][3] ^ co));
                #pragma unroll
                for (int j = 0; j < 4; ++j) {
                    h2 pa = r0.h[j]*wqb[pp][0] + r1.h[j]*wqb[pp][1]
                          + r2.h[j]*wqb[pp][2] + r3.h[j]*wqb[pp][3];
                    const h2 lf = (pp==0) ? fz[j] : (pp==1) ? fx[j] : fy[j];
                    comb[cc][j] += pa * lf;
                }
            }
            // volume (8 taps, L1-hot 16 KB table)
            #pragma unroll
            for (int dz = 0; dz < 2; ++dz)
                #pragma unroll
                for (int dy = 0; dy < 2; ++dy)
                    #pragma unroll
                    for (int dx = 0; dx < 2; ++dx) {
                        UH V;
                        V.v = *(const uint4*)(wsb + vbase + dz*3200 + dy*640 + dx*128 + co);
                        const h2 w = wvb[dz*4+dy*2+dx];
                        #pragma unroll
                        for (int j = 0; j < 4; ++j) comb[cc][j] += V.h[j] * w;
                    }
        }
        // MLP layer 1 via f16 MFMA; comb is already the A-fragment
        union AF { f16x8 v; h2 h[4]; } A0, A1;
        #pragma unroll
        for (int j = 0; j < 4; ++j) { A0.h[j] = comb[0][j]; A1.h[j] = comb[1][j]; }
        f32x4 acc0 = {0.f,0.f,0.f,0.f};
        f32x4 acc1 = {0.f,0.f,0.f,0.f};
        f32x4 acc2 = {0.f,0.f,0.f,0.f};
        f32x4 acc3 = {0.f,0.f,0.f,0.f};
        acc0 = __builtin_amdgcn_mfma_f32_16x16x32_f16(A0.v, wfrag[0][0], acc0, 0, 0, 0);
        acc0 = __builtin_amdgcn_mfma_f32_16x16x32_f16(A1.v, wfrag[0][1], acc0, 0, 0, 0);
        acc1 = __builtin_amdgcn_mfma_f32_16x16x32_f16(A0.v, wfrag[1][0], acc1, 0, 0, 0);
        acc1 = __builtin_amdgcn_mfma_f32_16x16x32_f16(A1.v, wfrag[1][1], acc1, 0, 0, 0);
        acc2 = __builtin_amdgcn_mfma_f32_16x16x32_f16(A0.v, wfrag[2][0], acc2, 0, 0, 0);
        acc2 = __builtin_amdgcn_mfma_f32_16x16x32_f16(A1.v, wfrag[2][1], acc2, 0, 0, 0);
        acc3 = __builtin_amdgcn_mfma_f32_16x16x32_f16(A0.v, wfrag[3][0], acc3, 0, 0, 0);
        acc3 = __builtin_amdgcn_mfma_f32_16x16x32_f16(A1.v, wfrag[3][1], acc3, 0, 0, 0);
        // layer 2: relu + dot with w2; reduce across the 16 C-layout columns
        float sr[4];
        #pragma unroll
        for (int r = 0; r < 4; ++r) {
            float s = fmaxf(acc0[r] + b1v[0], 0.f) * w2v[0];
            s = fmaf(fmaxf(acc1[r] + b1v[1], 0.f), w2v[1], s);
            s = fmaf(fmaxf(acc2[r] + b1v[2], 0.f), w2v[2], s);
            s = fmaf(fmaxf(acc3[r] + b1v[3], 0.f), w2v[3], s);
            sr[r] = s;
        }
        #pragma unroll
        for (int m = 1; m <= 8; m <<= 1) {
            #pragma unroll
            for (int r = 0; r < 4; ++r) sr[r] += __shfl_xor(sr[r], m, 64);
        }
        if (p == 0) {
            float4 o;
            o.x = sr[0] + b2v;
            o.y = sr[1] + b2v;
            o.z = sr[2] + b2v;
            o.w = sr[3] + b2v;
            *(float4*)(out + pbase + (fg << 2)) = o;
        }
    }
}

// ---------------------------------------------------------------------------
// Fallback (only if ws_size is too small): slow but correct, thread-per-point.
// ---------------------------------------------------------------------------
__global__ __launch_bounds__(256) void ga_naive(
    const float* __restrict__ coords,
    const float* __restrict__ lx, const float* __restrict__ ly, const float* __restrict__ lz,
    const float* __restrict__ pxy, const float* __restrict__ pyz, const float* __restrict__ pzx,
    const float* __restrict__ vol,
    const float* __restrict__ w1, const float* __restrict__ b1,
    const float* __restrict__ w2, const float* __restrict__ b2,
    float* __restrict__ out)
{
    const int n = blockIdx.x * blockDim.x + threadIdx.x;
    if (n >= NPTS) return;
    int lidx[3], pidx[3], vidx[3];
    float lww[3], lwm[3], pww[3], pwm[3], vww[3], vwm[3];
    for (int c = 0; c < 3; ++c) {
        const float cv = coords[3*n + c];
        const float u = (cv + 1.f)*0.5f;
        float pos = fminf(fmaxf(u*511.f, 0.f), 511.f);
        float i0 = fminf(floorf(pos), 510.f);
        lidx[c] = (int)i0; lww[c] = pos - i0; lwm[c] = 1.f - lww[c];
        float pq = fminf(fmaxf(u*19.f, 0.f), 19.f);
        float pi0 = fminf(floorf(pq), 18.f);
        pidx[c] = (int)pi0; pww[c] = pq - pi0; pwm[c] = 1.f - pww[c];
        float vq = fminf(fmaxf(u*4.f, 0.f), 4.f);
        float vi0 = fminf(floorf(vq), 3.f);
        vidx[c] = (int)vi0; vww[c] = vq - vi0; vwm[c] = 1.f - vww[c];
    }
    float comb[64];
    for (int f = 0; f < 64; ++f) {
        const float fxv = lwm[0]*lx[f*512+lidx[0]] + lww[0]*lx[f*512+lidx[0]+1];
        const float fyv = lwm[1]*ly[f*512+lidx[1]] + lww[1]*ly[f*512+lidx[1]+1];
        const float fzv = lwm[2]*lz[f*512+lidx[2]] + lww[2]*lz[f*512+lidx[2]+1];
        const int bxy = f*400 + pidx[1]*20 + pidx[0];
        const float pxyv = pwm[1]*pwm[0]*pxy[bxy]    + pwm[1]*pww[0]*pxy[bxy+1]
                         + pww[1]*pwm[0]*pxy[bxy+20] + pww[1]*pww[0]*pxy[bxy+21];
        const int byz = f*400 + pidx[2]*20 + pidx[1];
        const float pyzv = pwm[2]*pwm[1]*pyz[byz]    + pwm[2]*pww[1]*pyz[byz+1]
                         + pww[2]*pwm[1]*pyz[byz+20] + pww[2]*pww[1]*pyz[byz+21];
        const int bzx = f*400 + pidx[0]*20 + pidx[2];
        const float pzxv = pwm[0]*pwm[2]*pzx[bzx]    + pwm[0]*pww[2]*pzx[bzx+1]
                         + pww[0]*pwm[2]*pzx[bzx+20] + pww[0]*pww[2]*pzx[bzx+21];
        const int bv = f*125 + (vidx[2]*5 + vidx[1])*5 + vidx[0];
        float vv = 0.f;
        for (int dz = 0; dz < 2; ++dz)
            for (int dy = 0; dy < 2; ++dy)
                for (int dx = 0; dx < 2; ++dx) {
                    const float w = (dz ? vww[2] : vwm[2]) * (dy ? vww[1] : vwm[1]) * (dx ? vww[0] : vwm[0]);
                    vv += w * vol[bv + dz*25 + dy*5 + dx];
                }
        comb[f] = fxv*fyv*fzv + pxyv*fzv + pyzv*fxv + pzxv*fyv + vv;
    }
    float o = b2[0];
    for (int gg = 0; gg < 64; ++gg) {
        float h = b1[gg];
        for (int f = 0; f < 64; ++f) h = fmaf(comb[f], w1[gg*64 + f], h);
        o = fmaf(fmaxf(h, 0.f), w2[gg], o);
    }
    out[n] = o;
}

extern "C" void kernel_launch(void* const* d_in, const int* in_sizes, int n_in,
                              void* d_out, int out_size, void* d_ws, size_t ws_size,
                              hipStream_t stream)
{
    const float* coords = (const float*)d_in[0];
    const float* lx  = (const float*)d_in[1];
    const float* ly  = (const float*)d_in[2];
    const float* lz  = (const float*)d_in[3];
    const float* pxy = (const float*)d_in[4];
    const float* pyz = (const float*)d_in[5];
    const float* pzx = (const float*)d_in[6];
    const float* vol = (const float*)d_in[7];
    const float* w1  = (const float*)d_in[8];
    const float* b1  = (const float*)d_in[9];
    const float* w2  = (const float*)d_in[10];
    const float* b2  = (const float*)d_in[11];
    float* out = (float*)d_out;
    if (ws_size >= (size_t)WS_TOTAL_BYTES) {
        u32* ws = (u32*)d_ws;
        ga_prep<<<dim3(550), dim3(256), 0, stream>>>(lx, ly, lz, pxy, pyz, pzx, vol, ws);
        ga_main<<<dim3(256), dim3(1024), 0, stream>>>(coords, w1, b1, w2, b2, ws, out);
    } else {
        ga_naive<<<dim3(4096), dim3(256), 0, stream>>>(coords, lx, ly, lz, pxy, pyz, pzx, vol,
                                                       w1, b1, w2, b2, out);
    }
}

// Round 4
// 248.252 us; speedup vs baseline: 1.4376x; 1.2368x over previous
//
#include <hip/hip_runtime.h>

typedef unsigned int u32;
typedef unsigned short u16;
typedef _Float16 half_t;
typedef half_t h2   __attribute__((ext_vector_type(2)));
typedef half_t f16x8 __attribute__((ext_vector_type(8)));
typedef float  f32x4 __attribute__((ext_vector_type(4)));

#define NPTS 1048576

// workspace dword layout (f16 feature-pair tables, built by ga_prep from fp32)
#define WS_LINE_DW   0        // 3*511*2*32 = 98112 dw: [line][i0][tap][fpair]
#define WS_VOL_DW    98112    // 125*32     =  4000 dw: [z*25+y*5+x][fpair]
#define WS_PLANE_DW  102112   // 3*400*32   = 38400 dw: [plane][row][swizzled chunk][fpair]
#define WS_TOTAL_DW  140512
#define WS_TOTAL_BYTES (WS_TOTAL_DW * 4)

// LDS layout (dwords): planes xy,yz at 0 (25600 dw), volume at 25600 (125 rows x 36 dw)
#define LDS_VOL_DW   25600
#define LDS_TOTAL_DW 30100        // 120,400 B -> 1 block/CU, 16 waves
#define VOLB         (LDS_VOL_DW*4)

__device__ __forceinline__ u32 pkh(float a, float b) {
    union { h2 h; u32 u; } r;
    r.h = (h2){(half_t)a, (half_t)b};
    return r.u;
}
__device__ __forceinline__ h2 bc(float w) {
    half_t h = (half_t)w;
    return (h2){h, h};
}

// ---------------------------------------------------------------------------
// Prep: fp32 inputs -> f16 feature-pair tables in d_ws. (unchanged from r3)
// ---------------------------------------------------------------------------
__global__ __launch_bounds__(256) void ga_prep(
    const float* __restrict__ lx, const float* __restrict__ ly, const float* __restrict__ lz,
    const float* __restrict__ pxy, const float* __restrict__ pyz, const float* __restrict__ pzx,
    const float* __restrict__ vol, u32* __restrict__ ws)
{
    const int stride = gridDim.x * blockDim.x;
    for (int t = blockIdx.x * blockDim.x + threadIdx.x; t < WS_TOTAL_DW; t += stride) {
        if (t < WS_VOL_DW) {
            const int l  = t / 32704;           // 511*64
            const int r  = t - l * 32704;
            const int i0 = r >> 6;              // 0..510
            const int w  = r & 63;
            const int tap = w >> 5;
            const int fp  = w & 31;
            const float* L = (l == 0) ? lx : (l == 1) ? ly : lz;
            ws[t] = pkh(L[(2*fp)*512 + i0 + tap], L[(2*fp+1)*512 + i0 + tap]);
        } else if (t < WS_PLANE_DW) {
            const int r = t - WS_VOL_DW;
            const int vox = r >> 5;
            const int fp  = r & 31;
            ws[t] = pkh(vol[(2*fp)*125 + vox], vol[(2*fp+1)*125 + vox]);
        } else {
            const int r  = t - WS_PLANE_DW;
            const int pp = r / 12800;
            const int rr = r - pp * 12800;
            const int row = rr >> 5;            // 0..399 (= y*20+x)
            const int c   = rr & 31;            // fpair index
            const int chunk = c >> 2;
            const int ci    = c & 3;
            const int pos = ((chunk ^ (row & 7)) << 2) + ci;  // XOR swizzle
            const float* P = (pp == 0) ? pxy : (pp == 1) ? pyz : pzx;
            const int f = c * 2;
            ws[WS_PLANE_DW + pp*12800 + (row << 5) + pos] =
                pkh(P[f*400 + row], P[(f+1)*400 + row]);
        }
    }
}

// ---------------------------------------------------------------------------
// Main: lane = (point p = lane&15, feature group fg = lane>>4).
// LDS: planes xy,yz (102.4 KB) + volume (18 KB padded). Plane zx + lines from
// L2. Coords prefetched one iteration ahead. Volume read first (LDS) while
// line/pzx global loads are in flight.
// ---------------------------------------------------------------------------
__global__ __launch_bounds__(1024, 4) void ga_main(
    const float* __restrict__ coords,
    const float* __restrict__ w1,
    const float* __restrict__ b1,
    const float* __restrict__ w2,
    const float* __restrict__ b2,
    const u32* __restrict__ ws,
    float* __restrict__ out)
{
    __shared__ u32 sP[LDS_TOTAL_DW];   // 120,400 B
    const int tid = threadIdx.x;
    {
        // planes xy,yz: 25600 dw = 6400 uint4, contiguous copy
        const uint4* src = (const uint4*)(ws + WS_PLANE_DW);
        uint4* dst = (uint4*)sP;
        #pragma unroll
        for (int i = 0; i < 7; ++i) {
            int idx = tid + i * 1024;
            if (idx < 6400) dst[idx] = src[idx];
        }
        // volume: 4000 dw = 1000 uint4; row vox (8 uint4) -> padded row vox*9
        if (tid < 1000) {
            const int vox = tid >> 3, ch = tid & 7;
            ((uint4*)(sP + LDS_VOL_DW))[vox*9 + ch] = ((const uint4*)(ws + WS_VOL_DW))[tid];
        }
    }
    __syncthreads();

    const int lane = tid & 63;
    const int wave = tid >> 6;       // 0..15
    const int p    = lane & 15;
    const int fg   = lane >> 4;      // 0..3
    const int wgbase = blockIdx.x << 12;   // 4096 points per workgroup

    // w1 B-fragments (f16): wfrag[t][h][j] = f16(w1[16t + p][h*32 + fg*8 + j])
    f16x8 wfrag[4][2];
    #pragma unroll
    for (int t = 0; t < 4; ++t) {
        #pragma unroll
        for (int h = 0; h < 2; ++h) {
            const float* src = w1 + ((16*t + p)*64 + h*32 + fg*8);
            f16x8 w;
            #pragma unroll
            for (int e = 0; e < 8; ++e) w[e] = (half_t)src[e];
            wfrag[t][h] = w;
        }
    }
    float b1v[4], w2v[4];
    #pragma unroll
    for (int t = 0; t < 4; ++t) { b1v[t] = b1[16*t + p]; w2v[t] = w2[16*t + p]; }
    const float b2v = b2[0];

    const char* wsb = (const char*)ws;
    const char* spb = (const char*)sP;

    // coords prefetch (software pipeline, depth 1)
    float cx = coords[3*(wgbase + (wave<<4) + p) + 0];
    float cy = coords[3*(wgbase + (wave<<4) + p) + 1];
    float cz = coords[3*(wgbase + (wave<<4) + p) + 2];

    for (int g = wave; g < 256; g += 16) {
        const int pbase = wgbase + (g << 4);
        // issue next iteration's coords now (no dependents until loop end)
        const int gn = (g + 16 < 256) ? g + 16 : g;
        const int ptn = wgbase + (gn << 4) + p;
        const float nx = coords[3*ptn + 0];
        const float ny = coords[3*ptn + 1];
        const float nz = coords[3*ptn + 2];

        int lidx[3], pidx[3], vidx[3];
        float lww[3], lwm[3], pww[3], pwm[3], vww[3], vwm[3];
        {
            const float uu[3] = { (cx+1.f)*0.5f, (cy+1.f)*0.5f, (cz+1.f)*0.5f };
            #pragma unroll
            for (int c = 0; c < 3; ++c) {
                float pos = fminf(fmaxf(uu[c]*511.f, 0.f), 511.f);
                float i0 = fminf(floorf(pos), 510.f);
                lidx[c] = (int)i0; lww[c] = pos - i0; lwm[c] = 1.f - lww[c];
                float pq = fminf(fmaxf(uu[c]*19.f, 0.f), 19.f);
                float pi0 = fminf(floorf(pq), 18.f);
                pidx[c] = (int)pi0; pww[c] = pq - pi0; pwm[c] = 1.f - pww[c];
                float vq = fminf(fmaxf(uu[c]*4.f, 0.f), 4.f);
                float vi0 = fminf(floorf(vq), 3.f);
                vidx[c] = (int)vi0; vww[c] = vq - vi0; vwm[c] = 1.f - vww[c];
            }
        }
        // line byte bases: [c][i0] block = 256 B; tap1 at +128; cc chunk at +64
        int laddr[3];
        #pragma unroll
        for (int c = 0; c < 3; ++c)
            laddr[c] = (c*511 + lidx[c])*256 + fg*16;
        // plane corner weights + addresses (xy,yz -> LDS bytes; zx -> ws bytes)
        // plane0=xy(gx=x,gy=y)  plane1=yz(gx=y,gy=z)  plane2=zx(gx=z,gy=x)
        float wqf[3][4];
        int paddr[3][4];
        #pragma unroll
        for (int pp = 0; pp < 3; ++pp) {
            const int a = (pp==0)?0:(pp==1)?1:2;    // gx axis (col)
            const int b = (pp==0)?1:(pp==1)?2:0;    // gy axis (row)
            wqf[pp][0] = pwm[b]*pwm[a]; wqf[pp][1] = pwm[b]*pww[a];
            wqf[pp][2] = pww[b]*pwm[a]; wqf[pp][3] = pww[b]*pww[a];
            const int r00 = pidx[b]*20 + pidx[a];
            const int base = (pp == 2) ? (WS_PLANE_DW*4 + 2*51200) : pp*51200;
            const int roff[4] = {0, 1, 20, 21};
            #pragma unroll
            for (int k = 0; k < 4; ++k) {
                const int r = r00 + roff[k];
                paddr[pp][k] = base + r*128 + ((fg ^ (r & 7)) << 4);
            }
        }
        // volume: LDS, padded rows (144 B); 8 corner taps
        const int vox00 = (vidx[2]*5 + vidx[1])*5 + vidx[0];
        const int vb = VOLB + vox00*144 + fg*16;
        float wvf[8];
        #pragma unroll
        for (int dz = 0; dz < 2; ++dz)
            #pragma unroll
            for (int dy = 0; dy < 2; ++dy)
                #pragma unroll
                for (int dx = 0; dx < 2; ++dx)
                    wvf[dz*4+dy*2+dx] = (dz?vww[2]:vwm[2])*(dy?vww[1]:vwm[1])*(dx?vww[0]:vwm[0]);

        // h2 weight broadcasts
        h2 wlm[3], wlw[3], wqb[3][4], wvb[8];
        #pragma unroll
        for (int c = 0; c < 3; ++c) { wlm[c] = bc(lwm[c]); wlw[c] = bc(lww[c]); }
        #pragma unroll
        for (int pp = 0; pp < 3; ++pp)
            #pragma unroll
            for (int k = 0; k < 4; ++k) wqb[pp][k] = bc(wqf[pp][k]);
        #pragma unroll
        for (int t = 0; t < 8; ++t) wvb[t] = bc(wvf[t]);

        union UH { uint4 v; h2 h[4]; };
        h2 comb[2][4];
        #pragma unroll
        for (int cc = 0; cc < 2; ++cc) {
            const int co = cc * 64;
            // ---- global loads first: lines (6) + plane-zx (4) ----
            UH X0, X1, Y0, Y1, Z0, Z1;
            X0.v = *(const uint4*)(wsb + laddr[0] + co);
            X1.v = *(const uint4*)(wsb + laddr[0] + co + 128);
            Y0.v = *(const uint4*)(wsb + laddr[1] + co);
            Y1.v = *(const uint4*)(wsb + laddr[1] + co + 128);
            Z0.v = *(const uint4*)(wsb + laddr[2] + co);
            Z1.v = *(const uint4*)(wsb + laddr[2] + co + 128);
            UH q0, q1, q2, q3;
            q0.v = *(const uint4*)(wsb + (paddr[2][0] ^ co));
            q1.v = *(const uint4*)(wsb + (paddr[2][1] ^ co));
            q2.v = *(const uint4*)(wsb + (paddr[2][2] ^ co));
            q3.v = *(const uint4*)(wsb + (paddr[2][3] ^ co));
            // ---- volume from LDS while globals fly ----
            UH V[8];
            #pragma unroll
            for (int dz = 0; dz < 2; ++dz)
                #pragma unroll
                for (int dy = 0; dy < 2; ++dy)
                    #pragma unroll
                    for (int dx = 0; dx < 2; ++dx)
                        V[dz*4+dy*2+dx].v = *(const uint4*)(spb + vb + (dz*25+dy*5+dx)*144 + co);
            #pragma unroll
            for (int j = 0; j < 4; ++j) {
                h2 s = V[0].h[j]*wvb[0] + V[1].h[j]*wvb[1]
                     + V[2].h[j]*wvb[2] + V[3].h[j]*wvb[3];
                s += V[4].h[j]*wvb[4] + V[5].h[j]*wvb[5]
                   + V[6].h[j]*wvb[6] + V[7].h[j]*wvb[7];
                comb[cc][j] = s;
            }
            // ---- line lerps ----
            h2 fx[4], fy[4], fz[4];
            #pragma unroll
            for (int j = 0; j < 4; ++j) {
                fx[j] = X0.h[j]*wlm[0] + X1.h[j]*wlw[0];
                fy[j] = Y0.h[j]*wlm[1] + Y1.h[j]*wlw[1];
                fz[j] = Z0.h[j]*wlm[2] + Z1.h[j]*wlw[2];
            }
            #pragma unroll
            for (int j = 0; j < 4; ++j) comb[cc][j] += fx[j]*fy[j]*fz[j];
            // ---- planes xy,yz from LDS ----
            #pragma unroll
            for (int pp = 0; pp < 2; ++pp) {
                UH r0, r1, r2, r3;
                r0.v = *(const uint4*)(spb + (paddr[pp][0] ^ co));
                r1.v = *(const uint4*)(spb + (paddr[pp][1] ^ co));
                r2.v = *(const uint4*)(spb + (paddr[pp][2] ^ co));
                r3.v = *(const uint4*)(spb + (paddr[pp][3] ^ co));
                #pragma unroll
                for (int j = 0; j < 4; ++j) {
                    h2 pa = r0.h[j]*wqb[pp][0] + r1.h[j]*wqb[pp][1]
                          + r2.h[j]*wqb[pp][2] + r3.h[j]*wqb[pp][3];
                    const h2 lf = (pp==0) ? fz[j] : fx[j];
                    comb[cc][j] += pa * lf;
                }
            }
            // ---- plane zx from prefetched global regs ----
            #pragma unroll
            for (int j = 0; j < 4; ++j) {
                h2 pa = q0.h[j]*wqb[2][0] + q1.h[j]*wqb[2][1]
                      + q2.h[j]*wqb[2][2] + q3.h[j]*wqb[2][3];
                comb[cc][j] += pa * fy[j];
            }
        }
        // MLP layer 1 via f16 MFMA; comb is already the A-fragment
        union AF { f16x8 v; h2 h[4]; } A0, A1;
        #pragma unroll
        for (int j = 0; j < 4; ++j) { A0.h[j] = comb[0][j]; A1.h[j] = comb[1][j]; }
        f32x4 acc0 = {0.f,0.f,0.f,0.f};
        f32x4 acc1 = {0.f,0.f,0.f,0.f};
        f32x4 acc2 = {0.f,0.f,0.f,0.f};
        f32x4 acc3 = {0.f,0.f,0.f,0.f};
        acc0 = __builtin_amdgcn_mfma_f32_16x16x32_f16(A0.v, wfrag[0][0], acc0, 0, 0, 0);
        acc0 = __builtin_amdgcn_mfma_f32_16x16x32_f16(A1.v, wfrag[0][1], acc0, 0, 0, 0);
        acc1 = __builtin_amdgcn_mfma_f32_16x16x32_f16(A0.v, wfrag[1][0], acc1, 0, 0, 0);
        acc1 = __builtin_amdgcn_mfma_f32_16x16x32_f16(A1.v, wfrag[1][1], acc1, 0, 0, 0);
        acc2 = __builtin_amdgcn_mfma_f32_16x16x32_f16(A0.v, wfrag[2][0], acc2, 0, 0, 0);
        acc2 = __builtin_amdgcn_mfma_f32_16x16x32_f16(A1.v, wfrag[2][1], acc2, 0, 0, 0);
        acc3 = __builtin_amdgcn_mfma_f32_16x16x32_f16(A0.v, wfrag[3][0], acc3, 0, 0, 0);
        acc3 = __builtin_amdgcn_mfma_f32_16x16x32_f16(A1.v, wfrag[3][1], acc3, 0, 0, 0);
        // layer 2: relu + dot with w2; reduce across the 16 C-layout columns
        float sr[4];
        #pragma unroll
        for (int r = 0; r < 4; ++r) {
            float s = fmaxf(acc0[r] + b1v[0], 0.f) * w2v[0];
            s = fmaf(fmaxf(acc1[r] + b1v[1], 0.f), w2v[1], s);
            s = fmaf(fmaxf(acc2[r] + b1v[2], 0.f), w2v[2], s);
            s = fmaf(fmaxf(acc3[r] + b1v[3], 0.f), w2v[3], s);
            sr[r] = s;
        }
        #pragma unroll
        for (int m = 1; m <= 8; m <<= 1) {
            #pragma unroll
            for (int r = 0; r < 4; ++r) sr[r] += __shfl_xor(sr[r], m, 64);
        }
        if (p == 0) {
            float4 o;
            o.x = sr[0] + b2v;
            o.y = sr[1] + b2v;
            o.z = sr[2] + b2v;
            o.w = sr[3] + b2v;
            *(float4*)(out + pbase + (fg << 2)) = o;
        }
        cx = nx; cy = ny; cz = nz;
    }
}

// ---------------------------------------------------------------------------
// Fallback (only if ws_size is too small): slow but correct, thread-per-point.
// ---------------------------------------------------------------------------
__global__ __launch_bounds__(256) void ga_naive(
    const float* __restrict__ coords,
    const float* __restrict__ lx, const float* __restrict__ ly, const float* __restrict__ lz,
    const float* __restrict__ pxy, const float* __restrict__ pyz, const float* __restrict__ pzx,
    const float* __restrict__ vol,
    const float* __restrict__ w1, const float* __restrict__ b1,
    const float* __restrict__ w2, const float* __restrict__ b2,
    float* __restrict__ out)
{
    const int n = blockIdx.x * blockDim.x + threadIdx.x;
    if (n >= NPTS) return;
    int lidx[3], pidx[3], vidx[3];
    float lww[3], lwm[3], pww[3], pwm[3], vww[3], vwm[3];
    for (int c = 0; c < 3; ++c) {
        const float cv = coords[3*n + c];
        const float u = (cv + 1.f)*0.5f;
        float pos = fminf(fmaxf(u*511.f, 0.f), 511.f);
        float i0 = fminf(floorf(pos), 510.f);
        lidx[c] = (int)i0; lww[c] = pos - i0; lwm[c] = 1.f - lww[c];
        float pq = fminf(fmaxf(u*19.f, 0.f), 19.f);
        float pi0 = fminf(floorf(pq), 18.f);
        pidx[c] = (int)pi0; pww[c] = pq - pi0; pwm[c] = 1.f - pww[c];
        float vq = fminf(fmaxf(u*4.f, 0.f), 4.f);
        float vi0 = fminf(floorf(vq), 3.f);
        vidx[c] = (int)vi0; vww[c] = vq - vi0; vwm[c] = 1.f - vww[c];
    }
    float comb[64];
    for (int f = 0; f < 64; ++f) {
        const float fxv = lwm[0]*lx[f*512+lidx[0]] + lww[0]*lx[f*512+lidx[0]+1];
        const float fyv = lwm[1]*ly[f*512+lidx[1]] + lww[1]*ly[f*512+lidx[1]+1];
        const float fzv = lwm[2]*lz[f*512+lidx[2]] + lww[2]*lz[f*512+lidx[2]+1];
        const int bxy = f*400 + pidx[1]*20 + pidx[0];
        const float pxyv = pwm[1]*pwm[0]*pxy[bxy]    + pwm[1]*pww[0]*pxy[bxy+1]
                         + pww[1]*pwm[0]*pxy[bxy+20] + pww[1]*pww[0]*pxy[bxy+21];
        const int byz = f*400 + pidx[2]*20 + pidx[1];
        const float pyzv = pwm[2]*pwm[1]*pyz[byz]    + pwm[2]*pww[1]*pyz[byz+1]
                         + pww[2]*pwm[1]*pyz[byz+20] + pww[2]*pww[1]*pyz[byz+21];
        const int bzx = f*400 + pidx[0]*20 + pidx[2];
        const float pzxv = pwm[0]*pwm[2]*pzx[bzx]    + pwm[0]*pww[2]*pzx[bzx+1]
                         + pww[0]*pwm[2]*pzx[bzx+20] + pww[0]*pww[2]*pzx[bzx+21];
        const int bv = f*125 + (vidx[2]*5 + vidx[1])*5 + vidx[0];
        float vv = 0.f;
        for (int dz = 0; dz < 2; ++dz)
            for (int dy = 0; dy < 2; ++dy)
                for (int dx = 0; dx < 2; ++dx) {
                    const float w = (dz ? vww[2] : vwm[2]) * (dy ? vww[1] : vwm[1]) * (dx ? vww[0] : vwm[0]);
                    vv += w * vol[bv + dz*25 + dy*5 + dx];
                }
        comb[f] = fxv*fyv*fzv + pxyv*fzv + pyzv*fxv + pzxv*fyv + vv;
    }
    float o = b2[0];
    for (int gg = 0; gg < 64; ++gg) {
        float h = b1[gg];
        for (int f = 0; f < 64; ++f) h = fmaf(comb[f], w1[gg*64 + f], h);
        o = fmaf(fmaxf(h, 0.f), w2[gg], o);
    }
    out[n] = o;
}

extern "C" void kernel_launch(void* const* d_in, const int* in_sizes, int n_in,
                              void* d_out, int out_size, void* d_ws, size_t ws_size,
                              hipStream_t stream)
{
    const float* coords = (const float*)d_in[0];
    const float* lx  = (const float*)d_in[1];
    const float* ly  = (const float*)d_in[2];
    const float* lz  = (const float*)d_in[3];
    const float* pxy = (const float*)d_in[4];
    const float* pyz = (const float*)d_in[5];
    const float* pzx = (const float*)d_in[6];
    const float* vol = (const float*)d_in[7];
    const float* w1  = (const float*)d_in[8];
    const float* b1  = (const float*)d_in[9];
    const float* w2  = (const float*)d_in[10];
    const float* b2  = (const float*)d_in[11];
    float* out = (float*)d_out;
    if (ws_size >= (size_t)WS_TOTAL_BYTES) {
        u32* ws = (u32*)d_ws;
        ga_prep<<<dim3(550), dim3(256), 0, stream>>>(lx, ly, lz, pxy, pyz, pzx, vol, ws);
        ga_main<<<dim3(256), dim3(1024), 0, stream>>>(coords, w1, b1, w2, b2, ws, out);
    } else {
        ga_naive<<<dim3(4096), dim3(256), 0, stream>>>(coords, lx, ly, lz, pxy, pyz, pzx, vol,
                                                       w1, b1, w2, b2, out);
    }
}